// Round 13
// baseline (3051.845 us; speedup 1.0000x reference)
//
#include <hip/hip_runtime.h>
#include <math.h>

#define T_STEPS 1024
#define BATCH   512
#define DZ      256
#define DH      256
#define RANK    8
#define DY      16

// 512 blocks x 1024 threads (16 waves), ONE batch element per block.
// Aim: 2 blocks/CU co-resident (32 waves/CU). Evidence: co-residency
// tracks VGPR count, not LDS — R7 (VGPR 64, LDS 47KB) hit 41.8% occ
// (2 co-resident 8-wave blocks); R8-R10 (VGPR 108) pinned at 1 block.
// This kernel: VGPR 64 (verified cap for 1024-thr blocks), LDS ~31KB.
//
// 2-barrier structure (R12-validated, absmax 0.0039), single batch:
//   A -> {out(t-1) [waves 0-7], hp/zp/rz/gl [waves 8-11],
//         prefetch [waves 12-15], main dot2 partials [all]} -> B
//     -> {z-update [tid<256] || h-update [tid 256-511],
//         sclh publish [waves 12-15]} -> A
// Signal projection rz advanced pre-barrier with projected weights
// Pz = Wzo@W_zz, Pzi = Wzo@Wz_in (precomputed once per block).

typedef _Float16 f16;
typedef _Float16 h2 __attribute__((ext_vector_type(2)));

__device__ __forceinline__ h2 pack2(float a, float b) {
    h2 r; r.x = (f16)a; r.y = (f16)b; return r;
}
__device__ __forceinline__ h2 bc(unsigned u) { return __builtin_bit_cast(h2, u); }

__device__ __forceinline__ float dot2(h2 a, h2 b, float c) {
#if __has_builtin(__builtin_amdgcn_fdot2)
    return __builtin_amdgcn_fdot2(a, b, c, false);
#else
    return fmaf((float)a.x, (float)b.x, fmaf((float)a.y, (float)b.y, c));
#endif
}

__device__ __forceinline__ float fast_tanh(float x) {
    const float e = __expf(2.0f * x);
    return 1.0f - 2.0f / (e + 1.0f);
}

__global__ __launch_bounds__(1024, 4)
void nmrnn_kernel(
    const float* __restrict__ s, const float* __restrict__ c,
    const float* __restrict__ W_zz, const float* __restrict__ Wz_in,
    const float* __restrict__ bz_in, const float* __restrict__ Wz_out,
    const float* __restrict__ bz_out, const float* __restrict__ U,
    const float* __restrict__ V, const float* __restrict__ W_in,
    const float* __restrict__ b_in, const float* __restrict__ W_out,
    const float* __restrict__ b_out,
    float* __restrict__ out, float* __restrict__ states)
{
    __shared__ __align__(16) f16 tzh[DZ];        // tanh(z) f16
    __shared__ __align__(16) f16 thh[DH];        // tanh(h) f16
    __shared__ __align__(16) f16 sclh[64];       // [s_t|c_t] f16
    __shared__ __align__(16) float redz[4][DZ];  // z-dot partials [q][i]
    __shared__ __align__(16) float redh[4][DZ];  // W_in partials
    __shared__ __align__(16) f16 pz16[RANK][DZ]; // Wzo @ W_zz (projected)
    __shared__ __align__(16) f16 pzi16[RANK][64];// Wzo @ Wz_in
    __shared__ __align__(16) f16 vt16[RANK][DH]; // V^T f16
    __shared__ __align__(16) f16 ut16[RANK][DH]; // U^T f16
    __shared__ __align__(16) f16 wo16[DY][DH];   // W_out f16
    __shared__ float gl[RANK];
    __shared__ float bo[DY];
    // ~31 KB -> two blocks fit

    const int tid = threadIdx.x;
    const int i   = tid & 255;
    const int q   = tid >> 8;        // 0..3  K-quadrant
    const int w   = tid >> 6;        // 0..15 wave
    const int l32 = tid & 31;
    const int b   = blockIdx.x;      // one batch element

    const int oy = (tid >> 5) & 15;  // out group y (waves 0-7)
    const int rr = (tid >> 5) & 7;   // rank group (waves 8-11)
    const int px = tid & 63;         // prefetch index (waves 12-15, first 64)

    // ---- persistent f16-packed weights (44 VGPRs) ----
    h2 wzzp[32];
    #pragma unroll
    for (int m = 0; m < 16; ++m) {
        const float4 v4 = *(const float4*)&W_zz[i * 256 + (q << 6) + (m << 2)];
        wzzp[2 * m]     = pack2(v4.x, v4.y);
        wzzp[2 * m + 1] = pack2(v4.z, v4.w);
    }
    h2 wzip[8];
    #pragma unroll
    for (int m = 0; m < 4; ++m) {
        const float4 v4 = *(const float4*)&Wz_in[i * 64 + (q << 4) + (m << 2)];
        wzip[2 * m]     = pack2(v4.x, v4.y);
        wzip[2 * m + 1] = pack2(v4.z, v4.w);
    }
    h2 wip[4];
    #pragma unroll
    for (int m = 0; m < 2; ++m) {
        const float4 v4 = *(const float4*)&W_in[i * 32 + (q << 3) + (m << 2)];
        wip[2 * m]     = pack2(v4.x, v4.y);
        wip[2 * m + 1] = pack2(v4.z, v4.w);
    }

    // ---- stage small matrices as f16 ----
    {   // W_out: 4096 floats
        const int idx = tid * 4;
        const float4 v4 = *(const float4*)&W_out[idx];
        h2* dst = (h2*)&((f16*)wo16)[idx];
        dst[0] = pack2(v4.x, v4.y);
        dst[1] = pack2(v4.z, v4.w);
    }
    if (tid < 256) {  // transpose V, U -> f16
        #pragma unroll
        for (int r = 0; r < RANK; ++r) vt16[r][tid] = (f16)V[tid * RANK + r];
        #pragma unroll
        for (int r = 0; r < RANK; ++r) ut16[r][tid] = (f16)U[tid * RANK + r];
        tzh[tid] = (f16)0.f; thh[tid] = (f16)0.f;
    }
    if (tid < DY) bo[tid] = b_out[tid];
    if (tid < 64) {  // t=0 inputs
        const size_t base = (size_t)b * 32;
        sclh[tid] = (f16)((tid < 32) ? s[base + tid] : c[base + tid - 32]);
    }

    // ---- projected weights Pz = Wzo@W_zz, Pzi = Wzo@Wz_in (one-time) ----
    #pragma unroll
    for (int p = 0; p < 2; ++p) {
        const int r = q + 4 * p;
        const float* wrow = &Wz_out[r * 256];
        float a0 = 0.f, a1 = 0.f;
        #pragma unroll 4
        for (int k = 0; k < 256; k += 2) {
            a0 = fmaf(wrow[k],     W_zz[k * 256 + i],       a0);
            a1 = fmaf(wrow[k + 1], W_zz[(k + 1) * 256 + i], a1);
        }
        pz16[r][i] = (f16)(a0 + a1);
    }
    if (tid < 512) {
        const int r = tid >> 6, j = tid & 63;
        const float* wrow = &Wz_out[r * 256];
        float a0 = 0.f, a1 = 0.f;
        #pragma unroll 4
        for (int k = 0; k < 256; k += 2) {
            a0 = fmaf(wrow[k],     Wz_in[k * 64 + j],       a0);
            a1 = fmaf(wrow[k + 1], Wz_in[(k + 1) * 64 + j], a1);
        }
        pzi16[r][j] = (f16)(a0 + a1);
    }

    // state: z for tid<256 (neuron i), h for tid 256..511 (neuron i)
    const float bias_r = (tid < 256) ? bz_in[i]
                       : (tid < 512) ? b_in[i] : 0.f;
    float state_r = 0.f;

    // ---- waves 8-11 persistent: czb (const), rzb (recurrent) ----
    float czb = 0.f, rzb = 0.f;
    if (w >= 8 && w < 12) {
        float cz = 0.f;
        #pragma unroll
        for (int m = 0; m < 8; ++m) {
            const int k = l32 + 32 * m;
            cz = fmaf(bz_in[k], Wz_out[rr * 256 + k], cz);
        }
        #pragma unroll
        for (int off = 16; off >= 1; off >>= 1) cz += __shfl_xor(cz, off);
        const float bzo_r = bz_out[rr];
        czb = cz + bzo_r;
        rzb = bzo_r;
    }
    __syncthreads();   // A0: staging + projections done

    for (int t = 0; t < T_STEPS; ++t) {
        // ================= A..B =================
        float pfn = 0.f;
        if (w >= 12 && px < 64 && tid < 832 && t + 1 < T_STEPS) {
            const size_t base = ((size_t)(t + 1) * BATCH + b) * 32;
            pfn = (px < 32) ? s[base + px] : c[base + px - 32];
        }

        if (w < 8) {
            // out(t-1): 16 y-groups of 32 lanes
            if (t > 0) {
                const h2* tp = (const h2*)thh;
                const h2* wp = (const h2*)&wo16[oy][0];
                float o0 = 0.f, o1 = 0.f;
                o0 = dot2(tp[l32],      wp[l32],      o0);
                o1 = dot2(tp[l32 + 32], wp[l32 + 32], o1);
                o0 = dot2(tp[l32 + 64], wp[l32 + 64], o0);
                o1 = dot2(tp[l32 + 96], wp[l32 + 96], o1);
                float o = o0 + o1;
                #pragma unroll
                for (int off = 16; off >= 1; off >>= 1) o += __shfl_xor(o, off);
                if (l32 == 0) out[((size_t)(t - 1) * BATCH + b) * 16 + oy] = o + bo[oy];
            }
        } else if (w < 12) {
            // hp = tanh(h)@V[:,rr]; zp = tanh(z)@Pz[rr] + scl@Pzi[rr]
            // -> rzb update, sig, gl (pre-barrier)
            const h2* tp  = (const h2*)thh;
            const h2* vp  = (const h2*)&vt16[rr][0];
            const h2* tzp = (const h2*)tzh;
            const h2* pzp = (const h2*)&pz16[rr][0];
            float hp0 = 0.f, hp1 = 0.f, zp0 = 0.f, zp1 = 0.f;
            hp0 = dot2(tp[l32],       vp[l32],       hp0);
            hp1 = dot2(tp[l32 + 32],  vp[l32 + 32],  hp1);
            hp0 = dot2(tp[l32 + 64],  vp[l32 + 64],  hp0);
            hp1 = dot2(tp[l32 + 96],  vp[l32 + 96],  hp1);
            zp0 = dot2(tzp[l32],      pzp[l32],      zp0);
            zp1 = dot2(tzp[l32 + 32], pzp[l32 + 32], zp1);
            zp0 = dot2(tzp[l32 + 64], pzp[l32 + 64], zp0);
            zp1 = dot2(tzp[l32 + 96], pzp[l32 + 96], zp1);
            const h2* scp  = (const h2*)sclh;
            const h2* pzip = (const h2*)&pzi16[rr][0];
            zp0 = dot2(scp[l32], pzip[l32], zp0);
            float hp = hp0 + hp1, zp = zp0 + zp1;
            #pragma unroll
            for (int off = 16; off >= 1; off >>= 1) {
                hp += __shfl_xor(hp, off);
                zp += __shfl_xor(zp, off);
            }
            rzb = 0.99f * rzb + 0.01f * (zp + czb);
            const float sg = 1.0f / (1.0f + __expf(-rzb));
            if (l32 == 0) gl[rr] = sg * hp;
        }

        // main dot2 partials (all threads), q-quadrant, 2 az chains
        {
            float aza = 0.f, azb = 0.f, ah = 0.f;
            const uint4* tz = (const uint4*)&tzh[q << 6];
            #pragma unroll
            for (int m = 0; m < 8; ++m) {
                const uint4 u = tz[m];
                aza = dot2(wzzp[4 * m + 0], bc(u.x), aza);
                aza = dot2(wzzp[4 * m + 1], bc(u.y), aza);
                azb = dot2(wzzp[4 * m + 2], bc(u.z), azb);
                azb = dot2(wzzp[4 * m + 3], bc(u.w), azb);
            }
            const uint4* sp = (const uint4*)&sclh[q << 4];
            #pragma unroll
            for (int m = 0; m < 2; ++m) {
                const uint4 u = sp[m];
                aza = dot2(wzip[4 * m + 0], bc(u.x), aza);
                aza = dot2(wzip[4 * m + 1], bc(u.y), aza);
                azb = dot2(wzip[4 * m + 2], bc(u.z), azb);
                azb = dot2(wzip[4 * m + 3], bc(u.w), azb);
            }
            const uint4 uw = *(const uint4*)&sclh[q << 3];
            ah = dot2(wip[0], bc(uw.x), ah);
            ah = dot2(wip[1], bc(uw.y), ah);
            ah = dot2(wip[2], bc(uw.z), ah);
            ah = dot2(wip[3], bc(uw.w), ah);
            redz[q][i] = aza + azb;
            redh[q][i] = ah;
        }
        __syncthreads();  // B

        // ================= B..A' =================
        if (tid < 256) {
            // z-update (neuron i)
            const float tmp = redz[0][i] + redz[1][i]
                            + redz[2][i] + redz[3][i] + bias_r;
            state_r = 0.99f * state_r + 0.01f * tmp;
            tzh[i] = (f16)fast_tanh(state_r);
            states[((size_t)t * BATCH + b) * 512 + i] = state_r;
        } else if (tid < 512) {
            // h-update (neuron i); consumes gl published in phase A
            float t0 = redh[0][i] + redh[1][i]
                     + redh[2][i] + redh[3][i] + bias_r;
            float t1 = 0.f;
            #pragma unroll
            for (int r = 0; r < 4; ++r) {
                t0 = fmaf((float)ut16[2 * r][i],     gl[2 * r],     t0);
                t1 = fmaf((float)ut16[2 * r + 1][i], gl[2 * r + 1], t1);
            }
            state_r = 0.9f * state_r + 0.1f * (t0 + t1);
            thh[i] = (f16)fast_tanh(state_r);
            states[((size_t)t * BATCH + b) * 512 + 256 + i] = state_r;
        }
        if (w >= 12 && px < 64 && tid < 832 && t + 1 < T_STEPS)
            sclh[px] = (f16)pfn;
        __syncthreads();  // A
    }

    // ---- final out (t = T_STEPS-1) ----
    if (w < 8) {
        const h2* tp = (const h2*)thh;
        const h2* wp = (const h2*)&wo16[oy][0];
        float o0 = 0.f, o1 = 0.f;
        o0 = dot2(tp[l32],      wp[l32],      o0);
        o1 = dot2(tp[l32 + 32], wp[l32 + 32], o1);
        o0 = dot2(tp[l32 + 64], wp[l32 + 64], o0);
        o1 = dot2(tp[l32 + 96], wp[l32 + 96], o1);
        float o = o0 + o1;
        #pragma unroll
        for (int off = 16; off >= 1; off >>= 1) o += __shfl_xor(o, off);
        if (l32 == 0)
            out[((size_t)(T_STEPS - 1) * BATCH + b) * 16 + oy] = o + bo[oy];
    }
}

extern "C" void kernel_launch(void* const* d_in, const int* in_sizes, int n_in,
                              void* d_out, int out_size, void* d_ws, size_t ws_size,
                              hipStream_t stream) {
    const float* s     = (const float*)d_in[0];
    const float* c     = (const float*)d_in[1];
    const float* W_zz  = (const float*)d_in[2];
    const float* Wz_in = (const float*)d_in[3];
    const float* bz_in = (const float*)d_in[4];
    const float* Wz_out= (const float*)d_in[5];
    const float* bz_out= (const float*)d_in[6];
    const float* U     = (const float*)d_in[7];
    const float* V     = (const float*)d_in[8];
    const float* W_in  = (const float*)d_in[9];
    const float* b_in  = (const float*)d_in[10];
    const float* W_out = (const float*)d_in[11];
    const float* b_out = (const float*)d_in[12];

    float* out    = (float*)d_out;
    float* states = out + (size_t)T_STEPS * BATCH * DY;

    hipLaunchKernelGGL(nmrnn_kernel, dim3(BATCH), dim3(1024), 0, stream,
                       s, c, W_zz, Wz_in, bz_in, Wz_out, bz_out, U, V,
                       W_in, b_in, W_out, b_out, out, states);
}

// Round 14
// 2154.391 us; speedup vs baseline: 1.4166x; 1.4166x over previous
//
#include <hip/hip_runtime.h>
#include <math.h>

#define T_STEPS 1024
#define BATCH   512
#define DZ      256
#define DH      256
#define RANK    8
#define DY      16

// ===== Main kernel: 256 blocks x 512 threads, 2 batch elements/block. =====
// Thread (bb=tid>>8, i=tid&255) owns BOTH z_i and h_i of its batch element
// with FULL weight rows in registers (f16): W_zz row = 128 VGPR, Wz_in = 32,
// W_in = 16, U = 8. No cross-thread reductions for z/h at all -> two short,
// perfectly wave-balanced phases per step:
//   A: {rank-group gl via projected Pz/Pzi (R12-validated algebra),
//       full z-dot + W_in.s into registers, prefetch}  -> barrier B
//   B: {z/h updates, double-buffered LDS publish}      -> barrier A
// Register budget: __launch_bounds__(512, 1) -> 256-VGPR cap (law from
// R1-R13: budget = 256/N; (512,2) gave 108, HipKittens runs 512thr@249).
// The out-GEMV is moved to a post-kernel reading states_h (memory-bound).

typedef _Float16 f16;
typedef _Float16 h2 __attribute__((ext_vector_type(2)));

__device__ __forceinline__ h2 pack2(float a, float b) {
    h2 r; r.x = (f16)a; r.y = (f16)b; return r;
}
__device__ __forceinline__ h2 bc(unsigned u) { return __builtin_bit_cast(h2, u); }

__device__ __forceinline__ float dot2(h2 a, h2 b, float c) {
#if __has_builtin(__builtin_amdgcn_fdot2)
    return __builtin_amdgcn_fdot2(a, b, c, false);
#else
    return fmaf((float)a.x, (float)b.x, fmaf((float)a.y, (float)b.y, c));
#endif
}

__device__ __forceinline__ float fast_tanh(float x) {
    const float e = __expf(2.0f * x);
    return 1.0f - 2.0f / (e + 1.0f);
}

__global__ __launch_bounds__(512, 1)
void nmrnn_main(
    const float* __restrict__ s, const float* __restrict__ c,
    const float* __restrict__ W_zz, const float* __restrict__ Wz_in,
    const float* __restrict__ bz_in, const float* __restrict__ Wz_out,
    const float* __restrict__ bz_out, const float* __restrict__ U,
    const float* __restrict__ V, const float* __restrict__ W_in,
    const float* __restrict__ b_in,
    float* __restrict__ states)
{
    __shared__ __align__(16) f16 tzh[2][2][DZ];   // [buf][bb][k] tanh(z)
    __shared__ __align__(16) f16 thh[2][2][DH];   // tanh(h)
    __shared__ __align__(16) f16 sclh[2][2][64];  // [s|c]
    __shared__ __align__(16) f16 vt16[RANK][DH];  // V^T
    __shared__ __align__(16) f16 pz16[RANK][DZ];  // Wzo @ W_zz
    __shared__ __align__(16) f16 pzi16[RANK][64]; // Wzo @ Wz_in
    __shared__ float gl[2][RANK];                 // [bb][r]
    // ~14 KB

    const int tid = threadIdx.x;
    const int i   = tid & 255;
    const int bb  = tid >> 8;        // 0..1 batch half
    const int l32 = tid & 31;
    const int b0  = blockIdx.x * 2;
    // rank group: 16 groups of 32 lanes -> (rb, rr)
    const int gg = tid >> 5;
    const int rr = gg & 7;
    const int rb = gg >> 3;

    // ---- full-row f16 weights in registers (184 VGPRs) ----
    h2 wzz[128];
    #pragma unroll
    for (int m = 0; m < 64; ++m) {
        const float4 v4 = *(const float4*)&W_zz[i * 256 + (m << 2)];
        wzz[2 * m]     = pack2(v4.x, v4.y);
        wzz[2 * m + 1] = pack2(v4.z, v4.w);
    }
    h2 wzi[32];
    #pragma unroll
    for (int m = 0; m < 16; ++m) {
        const float4 v4 = *(const float4*)&Wz_in[i * 64 + (m << 2)];
        wzi[2 * m]     = pack2(v4.x, v4.y);
        wzi[2 * m + 1] = pack2(v4.z, v4.w);
    }
    h2 wi[16];
    #pragma unroll
    for (int m = 0; m < 8; ++m) {
        const float4 v4 = *(const float4*)&W_in[i * 32 + (m << 2)];
        wi[2 * m]     = pack2(v4.x, v4.y);
        wi[2 * m + 1] = pack2(v4.z, v4.w);
    }
    float uu[8];
    {
        const float4 a = *(const float4*)&U[i * 8];
        const float4 b4 = *(const float4*)&U[i * 8 + 4];
        uu[0]=a.x; uu[1]=a.y; uu[2]=a.z; uu[3]=a.w;
        uu[4]=b4.x; uu[5]=b4.y; uu[6]=b4.z; uu[7]=b4.w;
    }

    // ---- one-time staging ----
    if (tid < 256) {
        #pragma unroll
        for (int r = 0; r < RANK; ++r) vt16[r][tid] = (f16)V[tid * RANK + r];
    }
    // Pz = Wzo @ W_zz  (8x256, 4 entries/thread)
    #pragma unroll
    for (int p = 0; p < 4; ++p) {
        const int e = p * 512 + tid;
        const int r = e >> 8, col = e & 255;
        const float* wrow = &Wz_out[r * 256];
        float a0 = 0.f, a1 = 0.f;
        #pragma unroll 4
        for (int k = 0; k < 256; k += 2) {
            a0 = fmaf(wrow[k],     W_zz[k * 256 + col],       a0);
            a1 = fmaf(wrow[k + 1], W_zz[(k + 1) * 256 + col], a1);
        }
        pz16[r][col] = (f16)(a0 + a1);
    }
    {   // Pzi = Wzo @ Wz_in (8x64, 1 entry/thread)
        const int r = tid >> 6, j = tid & 63;
        const float* wrow = &Wz_out[r * 256];
        float a0 = 0.f, a1 = 0.f;
        #pragma unroll 4
        for (int k = 0; k < 256; k += 2) {
            a0 = fmaf(wrow[k],     Wz_in[k * 64 + j],       a0);
            a1 = fmaf(wrow[k + 1], Wz_in[(k + 1) * 64 + j], a1);
        }
        pzi16[r][j] = (f16)(a0 + a1);
    }
    tzh[0][bb][i] = (f16)0.f;
    thh[0][bb][i] = (f16)0.f;
    if (tid < 128) {  // t=0 inputs
        const int b2 = tid >> 6, rI = tid & 63;
        const size_t base = (size_t)(b0 + b2) * 32;
        sclh[0][b2][rI] = (f16)((rI < 32) ? s[base + rI] : c[base + rI - 32]);
    }

    const float bz = bz_in[i];
    const float bh = b_in[i];
    float z_r = 0.f, h_r = 0.f;

    // rank-group persistent: czb (const), rzb (recurrent)
    float czb, rzb;
    {
        float cz = 0.f;
        #pragma unroll
        for (int m = 0; m < 8; ++m) {
            const int k = l32 + 32 * m;
            cz = fmaf(bz_in[k], Wz_out[rr * 256 + k], cz);
        }
        #pragma unroll
        for (int off = 16; off >= 1; off >>= 1) cz += __shfl_xor(cz, off);
        const float bzo_r = bz_out[rr];
        czb = cz + bzo_r;
        rzb = bzo_r;
    }

    int cur = 0;
    __syncthreads();   // staging done

    for (int t = 0; t < T_STEPS; ++t) {
        // ================= PHASE A =================
        float pfn = 0.f;
        if (tid < 128 && t + 1 < T_STEPS) {
            const int b2 = tid >> 6, rI = tid & 63;
            const size_t base = ((size_t)(t + 1) * BATCH + b0 + b2) * 32;
            pfn = (rI < 32) ? s[base + rI] : c[base + rI - 32];
        }

        // rank duty (all 16 groups): hp, zp -> rzb -> gl[rb][rr]
        {
            const h2* tp  = (const h2*)&thh[cur][rb][0];
            const h2* vp  = (const h2*)&vt16[rr][0];
            const h2* tzp = (const h2*)&tzh[cur][rb][0];
            const h2* pzp = (const h2*)&pz16[rr][0];
            float hp0 = 0.f, hp1 = 0.f, zp0 = 0.f, zp1 = 0.f;
            hp0 = dot2(tp[l32],       vp[l32],       hp0);
            hp1 = dot2(tp[l32 + 32],  vp[l32 + 32],  hp1);
            hp0 = dot2(tp[l32 + 64],  vp[l32 + 64],  hp0);
            hp1 = dot2(tp[l32 + 96],  vp[l32 + 96],  hp1);
            zp0 = dot2(tzp[l32],      pzp[l32],      zp0);
            zp1 = dot2(tzp[l32 + 32], pzp[l32 + 32], zp1);
            zp0 = dot2(tzp[l32 + 64], pzp[l32 + 64], zp0);
            zp1 = dot2(tzp[l32 + 96], pzp[l32 + 96], zp1);
            const h2* scp  = (const h2*)&sclh[cur][rb][0];
            const h2* pzip = (const h2*)&pzi16[rr][0];
            zp0 = dot2(scp[l32], pzip[l32], zp0);
            float hp = hp0 + hp1, zp = zp0 + zp1;
            #pragma unroll
            for (int off = 16; off >= 1; off >>= 1) {
                hp += __shfl_xor(hp, off);
                zp += __shfl_xor(zp, off);
            }
            rzb = 0.99f * rzb + 0.01f * (zp + czb);
            const float sg = 1.0f / (1.0f + __expf(-rzb));
            if (l32 == 0) gl[rb][rr] = sg * hp;
        }

        // full z-dot (W_zz row) + Wz_in + W_in.s -> registers
        float az0 = 0.f, az1 = 0.f, az2 = 0.f, az3 = 0.f;
        float wh0 = 0.f, wh1 = 0.f;
        {
            const uint4* tz = (const uint4*)&tzh[cur][bb][0];
            #pragma unroll
            for (int m = 0; m < 32; ++m) {
                const uint4 u = tz[m];
                az0 = dot2(wzz[4 * m + 0], bc(u.x), az0);
                az1 = dot2(wzz[4 * m + 1], bc(u.y), az1);
                az2 = dot2(wzz[4 * m + 2], bc(u.z), az2);
                az3 = dot2(wzz[4 * m + 3], bc(u.w), az3);
            }
            const uint4* sp = (const uint4*)&sclh[cur][bb][0];
            #pragma unroll
            for (int m = 0; m < 8; ++m) {
                const uint4 u = sp[m];
                az0 = dot2(wzi[4 * m + 0], bc(u.x), az0);
                az1 = dot2(wzi[4 * m + 1], bc(u.y), az1);
                az2 = dot2(wzi[4 * m + 2], bc(u.z), az2);
                az3 = dot2(wzi[4 * m + 3], bc(u.w), az3);
            }
            #pragma unroll
            for (int m = 0; m < 4; ++m) {  // s-part only (first 32 entries)
                const uint4 u = sp[m];
                wh0 = dot2(wi[4 * m + 0], bc(u.x), wh0);
                wh1 = dot2(wi[4 * m + 1], bc(u.y), wh1);
                wh0 = dot2(wi[4 * m + 2], bc(u.z), wh0);
                wh1 = dot2(wi[4 * m + 3], bc(u.w), wh1);
            }
        }
        __syncthreads();  // B

        // ================= PHASE B =================
        const float zsum = (az0 + az1) + (az2 + az3) + bz;
        z_r = 0.99f * z_r + 0.01f * zsum;
        tzh[cur ^ 1][bb][i] = (f16)fast_tanh(z_r);
        states[((size_t)t * BATCH + b0 + bb) * 512 + i] = z_r;

        const float4 g0 = *(const float4*)&gl[bb][0];
        const float4 g1 = *(const float4*)&gl[bb][4];
        float hs0 = wh0 + bh, hs1 = wh1;
        hs0 = fmaf(uu[0], g0.x, hs0); hs1 = fmaf(uu[1], g0.y, hs1);
        hs0 = fmaf(uu[2], g0.z, hs0); hs1 = fmaf(uu[3], g0.w, hs1);
        hs0 = fmaf(uu[4], g1.x, hs0); hs1 = fmaf(uu[5], g1.y, hs1);
        hs0 = fmaf(uu[6], g1.z, hs0); hs1 = fmaf(uu[7], g1.w, hs1);
        h_r = 0.9f * h_r + 0.1f * (hs0 + hs1);
        thh[cur ^ 1][bb][i] = (f16)fast_tanh(h_r);
        states[((size_t)t * BATCH + b0 + bb) * 512 + 256 + i] = h_r;

        if (tid < 128 && t + 1 < T_STEPS)
            sclh[cur ^ 1][tid >> 6][tid & 63] = (f16)pfn;
        cur ^= 1;
        __syncthreads();  // A
    }
}

// ===== Post-kernel: out[t,b,:] = tanh(states_h[t,b,:]) @ W_out^T + b_out =====
// Memory-bound (~540 MB read). Block = 256 threads, 16 rows; thread (r,y)
// computes a full 256-MAC dot. LDS rows padded to kill bank conflicts.
__global__ __launch_bounds__(256)
void nmrnn_out(const float* __restrict__ states,
               const float* __restrict__ W_out,
               const float* __restrict__ b_out,
               float* __restrict__ out)
{
    __shared__ __align__(16) f16 th[16][264];   // +8 pad: rows hit distinct banks
    __shared__ __align__(16) f16 wo[16][258];   // +2 pad
    __shared__ float bo[DY];

    const int tid = threadIdx.x;
    #pragma unroll
    for (int it = 0; it < 16; ++it) {  // W_out stage: 4096 f32
        const int e = it * 256 + tid;
        wo[e >> 8][e & 255] = (f16)W_out[e];
    }
    if (tid < DY) bo[tid] = b_out[tid];

    const size_t row0 = (size_t)blockIdx.x * 16;
    #pragma unroll
    for (int it = 0; it < 16; ++it) {  // h rows: tanh -> f16
        const float v = states[(row0 + it) * 512 + 256 + tid];
        th[it][tid] = (f16)fast_tanh(v);
    }
    __syncthreads();

    const int r = tid >> 4, y = tid & 15;
    const h2* tp = (const h2*)&th[r][0];
    const h2* wp = (const h2*)&wo[y][0];
    float a0 = 0.f, a1 = 0.f, a2 = 0.f, a3 = 0.f;
    #pragma unroll
    for (int p = 0; p < 128; p += 4) {
        a0 = dot2(tp[p],     wp[p],     a0);
        a1 = dot2(tp[p + 1], wp[p + 1], a1);
        a2 = dot2(tp[p + 2], wp[p + 2], a2);
        a3 = dot2(tp[p + 3], wp[p + 3], a3);
    }
    out[row0 * 16 + tid] = (a0 + a1) + (a2 + a3) + bo[y];
}

extern "C" void kernel_launch(void* const* d_in, const int* in_sizes, int n_in,
                              void* d_out, int out_size, void* d_ws, size_t ws_size,
                              hipStream_t stream) {
    const float* s     = (const float*)d_in[0];
    const float* c     = (const float*)d_in[1];
    const float* W_zz  = (const float*)d_in[2];
    const float* Wz_in = (const float*)d_in[3];
    const float* bz_in = (const float*)d_in[4];
    const float* Wz_out= (const float*)d_in[5];
    const float* bz_out= (const float*)d_in[6];
    const float* U     = (const float*)d_in[7];
    const float* V     = (const float*)d_in[8];
    const float* W_in  = (const float*)d_in[9];
    const float* b_in  = (const float*)d_in[10];
    const float* W_out = (const float*)d_in[11];
    const float* b_out = (const float*)d_in[12];

    float* out    = (float*)d_out;
    float* states = out + (size_t)T_STEPS * BATCH * DY;

    hipLaunchKernelGGL(nmrnn_main, dim3(BATCH / 2), dim3(512), 0, stream,
                       s, c, W_zz, Wz_in, bz_in, Wz_out, bz_out, U, V,
                       W_in, b_in, states);

    hipLaunchKernelGGL(nmrnn_out, dim3(T_STEPS * BATCH / 16), dim3(256), 0,
                       stream, states, W_out, b_out, out);
}